// Round 8
// baseline (3699.787 us; speedup 1.0000x reference)
//
#include <hip/hip_runtime.h>

// ---------------------------------------------------------------------------
// MDGRU fused implementation, MI355X (gfx950)
//   B=64, T=2048, D=256, U=256, 3U=768
//   Kernel 1: proj[b][t][0:768] = X[b][t][:] @ kernel + bias   (f16 in d_ws)
//   Kernel 2: per-batch persistent GRU scan, ALL weights in named VGPRs.
//
//   Rounds 2-7: VGPR grant pinned at 1024/waves_per_block (= 2 blocks/CU
//   target) despite launch_bounds(,1)/(,2), waves_per_eu(2,2), 101KB LDS pad.
//   Surviving model: weight values are REMATERIALIZABLE (pure load+cvt+pack
//   chains from RK), so regalloc excludes them from pressure and re-executes
//   the chain at every use -> ~768 KB/block/step of f32 L2 traffic (~3400
//   cy/step, matches measured 1.4 us/step). Fix: opaque empty inline-asm
//   ("+v") defs on every weight reg -> remat illegal -> true pressure ~220
//   -> with launch_bounds(512,1) the allocator can grant 256.
//   Decisive check: VGPR_Count >= 200. (128 again => real scratch spills;
//   pivot to AGPR stash / LDS-hybrid next.)
// ---------------------------------------------------------------------------

typedef _Float16 half2_t __attribute__((ext_vector_type(2)));
typedef _Float16 half8_t __attribute__((ext_vector_type(8)));
typedef float    float4_t __attribute__((ext_vector_type(4)));

#define T_LEN 2048
#define B_SZ  64
#define D_IN  256
#define N3    768   // 3*U
#define U_SZ  256

// extract half2 p (p=0..3) from a half8 (sub-register access, free)
#define H2(v, p) __builtin_shufflevector((v), (v), 2*(p), 2*(p)+1)

__device__ __forceinline__ float fdot2f(half2_t a, half2_t b, float c) {
#if __has_builtin(__builtin_amdgcn_fdot2)
    return __builtin_amdgcn_fdot2(a, b, c, false);
#else
    return c + (float)a[0]*(float)b[0] + (float)a[1]*(float)b[1];
#endif
}

__device__ __forceinline__ float fast_sigmoid(float s) {
    return __builtin_amdgcn_rcpf(1.0f + __builtin_amdgcn_exp2f(-1.44269504f * s));
}
__device__ __forceinline__ float fast_tanh(float s) {
    return 1.0f - 2.0f * __builtin_amdgcn_rcpf(1.0f + __builtin_amdgcn_exp2f(2.88539008f * s));
}

// load 8 consecutive-k weights of one column (stride N3 f32) into a half8
__device__ __forceinline__ half8_t ldw8(const float* p) {
    half8_t h;
    #pragma unroll
    for (int e = 0; e < 8; ++e) h[e] = (_Float16)p[(size_t)e * N3];
    return h;
}

// ---------------------------------------------------------------------------
// Kernel 1: proj GEMM (unchanged, known-good: ~830 us).
// ---------------------------------------------------------------------------
#define GA_LD 264
#define NT_N  16          // 768/48
#define MT_M  2048        // 131072/64

__global__ __launch_bounds__(256) void proj_gemm(
    const float* __restrict__ X, const float* __restrict__ W,
    const float* __restrict__ bias, _Float16* __restrict__ proj)
{
    __shared__ __align__(16) _Float16 Ah[64 * GA_LD];   // [row][k]
    __shared__ __align__(16) _Float16 Wh[48 * GA_LD];   // [col][k]

    unsigned bid = blockIdx.x;
    unsigned idx = bid >> 3;
    unsigned mt  = (bid & 7) * (MT_M / 8) + (idx >> 4);
    unsigned nt  = idx & (NT_N - 1);
    int m0 = mt * 64, n0 = nt * 48;
    int tid = threadIdx.x;

    {
        int r = tid >> 6;
        int k = (tid & 63) * 4;
        #pragma unroll
        for (int i = 0; i < 16; ++i) {
            int row = i * 4 + r;
            float4_t v = *(const float4_t*)(X + (size_t)(m0 + row) * D_IN + k);
            _Float16* p = Ah + row * GA_LD + k;
            p[0] = (_Float16)v.x; p[1] = (_Float16)v.y;
            p[2] = (_Float16)v.z; p[3] = (_Float16)v.w;
        }
    }
    {
        int c  = tid & 63;
        int kk = tid >> 6;
        if (c < 48) {
            #pragma unroll 4
            for (int i = 0; i < 64; ++i) {
                int krow = i * 4 + kk;
                Wh[c * GA_LD + krow] = (_Float16)W[(size_t)krow * N3 + n0 + c];
            }
        }
    }
    __syncthreads();

    int r0 = (tid >> 4) << 2;
    int c  = tid & 15;
    float acc[4][3];
    #pragma unroll
    for (int rr = 0; rr < 4; ++rr)
        #pragma unroll
        for (int cc = 0; cc < 3; ++cc) acc[rr][cc] = 0.0f;

    for (int j = 0; j < 32; ++j) {
        half8_t av[4], wv[3];
        #pragma unroll
        for (int rr = 0; rr < 4; ++rr)
            av[rr] = *(const half8_t*)(Ah + (r0 + rr) * GA_LD + j * 8);
        #pragma unroll
        for (int cc = 0; cc < 3; ++cc)
            wv[cc] = *(const half8_t*)(Wh + (c + 16 * cc) * GA_LD + j * 8);
        #pragma unroll
        for (int rr = 0; rr < 4; ++rr)
            #pragma unroll
            for (int cc = 0; cc < 3; ++cc) {
                acc[rr][cc] = fdot2f(H2(av[rr],0), H2(wv[cc],0), acc[rr][cc]);
                acc[rr][cc] = fdot2f(H2(av[rr],1), H2(wv[cc],1), acc[rr][cc]);
                acc[rr][cc] = fdot2f(H2(av[rr],2), H2(wv[cc],2), acc[rr][cc]);
                acc[rr][cc] = fdot2f(H2(av[rr],3), H2(wv[cc],3), acc[rr][cc]);
            }
    }

    float bv[3];
    #pragma unroll
    for (int cc = 0; cc < 3; ++cc) bv[cc] = bias[n0 + c + 16 * cc];
    #pragma unroll
    for (int rr = 0; rr < 4; ++rr)
        #pragma unroll
        for (int cc = 0; cc < 3; ++cc)
            proj[(size_t)(m0 + r0 + rr) * N3 + (n0 + c + 16 * cc)] =
                (_Float16)(acc[rr][cc] + bv[cc]);
}

// ---------------------------------------------------------------------------
// Kernel 2: persistent GRU scan, 64 blocks x 512 threads.
// Weights: 48 named half8 vars (192 VGPRs), made NON-REMATERIALIZABLE via
// opaque "+v" inline asm so the allocator sees the true pressure.
//   phase1: thread(g=tid>>8, u=tid&255) owns U{z|r}[:,u]        (wa0..wa31)
//   phase2: thread(hcol=tid>>1, kh=tid&1) owns K-half Uh[:,hcol] (wb0..wb15)
//           partials combined via __shfl_xor(1) (in-wave partner)
// ---------------------------------------------------------------------------
__global__ __launch_bounds__(512, 1)
void gru_scan(
    const float* __restrict__ RK, const _Float16* __restrict__ proj,
    float* __restrict__ out)
{
    __shared__ __align__(16) _Float16 aH[U_SZ];    // f16 mirror of state
    __shared__ __align__(16) _Float16 raH[U_SZ];   // f16 r*a
    __shared__ float zS[U_SZ];
    __shared__ float aF[U_SZ];                     // fp32 state (authoritative)

    const int b    = blockIdx.x;
    const int tid  = threadIdx.x;
    const int g    = tid >> 8;       // 0=z, 1=r (wave-uniform)
    const int u    = tid & 255;
    const int hcol = tid >> 1;       // phase-2 Uh column
    const int kh   = tid & 1;        // phase-2 K-half

    // ---- phase-1 weights: U{z|r}[:,u], 32 named half8 regs (k = 8j..8j+7)
    half8_t wa0,wa1,wa2,wa3,wa4,wa5,wa6,wa7,
            wa8,wa9,wa10,wa11,wa12,wa13,wa14,wa15,
            wa16,wa17,wa18,wa19,wa20,wa21,wa22,wa23,
            wa24,wa25,wa26,wa27,wa28,wa29,wa30,wa31;
    {
        const float* wp = RK + (size_t)(g << 8) + u;   // RK[k][g*256+u]
        #define LA(i) wa##i = ldw8(wp + (size_t)(8*(i)) * N3);
        LA(0) LA(1) LA(2) LA(3) LA(4) LA(5) LA(6) LA(7)
        LA(8) LA(9) LA(10) LA(11) LA(12) LA(13) LA(14) LA(15)
        LA(16) LA(17) LA(18) LA(19) LA(20) LA(21) LA(22) LA(23)
        LA(24) LA(25) LA(26) LA(27) LA(28) LA(29) LA(30) LA(31)
        #undef LA
    }
    // ---- phase-2 weights: K-half of Uh[:,hcol], 16 named half8 regs
    half8_t wb0,wb1,wb2,wb3,wb4,wb5,wb6,wb7,
            wb8,wb9,wb10,wb11,wb12,wb13,wb14,wb15;
    {
        const float* wq = RK + (size_t)(kh * 128) * N3 + 512 + hcol;
        #define LB(i) wb##i = ldw8(wq + (size_t)(8*(i)) * N3);
        LB(0) LB(1) LB(2) LB(3) LB(4) LB(5) LB(6) LB(7)
        LB(8) LB(9) LB(10) LB(11) LB(12) LB(13) LB(14) LB(15)
        #undef LB
    }

    // ---- defeat rematerialization: every weight becomes an inline-asm def.
    #define OPQ8(a,b,c,d,e,f,gg,h) \
        asm volatile("" : "+v"(a), "+v"(b), "+v"(c), "+v"(d), \
                          "+v"(e), "+v"(f), "+v"(gg), "+v"(h));
    OPQ8(wa0,wa1,wa2,wa3,wa4,wa5,wa6,wa7)
    OPQ8(wa8,wa9,wa10,wa11,wa12,wa13,wa14,wa15)
    OPQ8(wa16,wa17,wa18,wa19,wa20,wa21,wa22,wa23)
    OPQ8(wa24,wa25,wa26,wa27,wa28,wa29,wa30,wa31)
    OPQ8(wb0,wb1,wb2,wb3,wb4,wb5,wb6,wb7)
    OPQ8(wb8,wb9,wb10,wb11,wb12,wb13,wb14,wb15)
    #undef OPQ8

    if (tid < U_SZ) { aF[tid] = 0.0f; aH[tid] = (_Float16)0.0f; }

    // x streams: phase1 proj[b][t][g*256+u], phase2 proj[b][t][512+hcol]
    const _Float16* px1 = proj + ((size_t)b * T_LEN) * N3 + (g << 8) + u;
    const _Float16* px2 = proj + ((size_t)b * T_LEN) * N3 + 512 + hcol;
    float x1 = (float)px1[0];
    float x2 = (float)px2[0];
    __syncthreads();

    for (int t = 0; t < T_LEN; ++t) {
        const float x1c = x1, x2c = x2;
        if (t + 1 < T_LEN) {
            x1 = (float)px1[(size_t)(t + 1) * N3];
            x2 = (float)px2[(size_t)(t + 1) * N3];
        }

        // ---- phase 1: z,r = sigmoid(a @ U{z,r} + x)   (all 8 waves)
        {
            float acc0 = 0.f, acc1 = 0.f, acc2 = 0.f, acc3 = 0.f;
            #define S1(j, WJ) { \
                half8_t av = *(const half8_t*)(aH + (j)*8); \
                acc0 = fdot2f(H2(av,0), H2(WJ,0), acc0); \
                acc1 = fdot2f(H2(av,1), H2(WJ,1), acc1); \
                acc2 = fdot2f(H2(av,2), H2(WJ,2), acc2); \
                acc3 = fdot2f(H2(av,3), H2(WJ,3), acc3); }
            S1(0,  wa0)  S1(1,  wa1)  S1(2,  wa2)  S1(3,  wa3)
            S1(4,  wa4)  S1(5,  wa5)  S1(6,  wa6)  S1(7,  wa7)
            S1(8,  wa8)  S1(9,  wa9)  S1(10, wa10) S1(11, wa11)
            S1(12, wa12) S1(13, wa13) S1(14, wa14) S1(15, wa15)
            S1(16, wa16) S1(17, wa17) S1(18, wa18) S1(19, wa19)
            S1(20, wa20) S1(21, wa21) S1(22, wa22) S1(23, wa23)
            S1(24, wa24) S1(25, wa25) S1(26, wa26) S1(27, wa27)
            S1(28, wa28) S1(29, wa29) S1(30, wa30) S1(31, wa31)
            #undef S1
            float sig = fast_sigmoid((acc0 + acc1) + (acc2 + acc3) + x1c);
            if (g == 0) zS[u]  = sig;
            else        raH[u] = (_Float16)(sig * aF[u]);     // r * a
        }
        __syncthreads();

        // ---- phase 2: h = tanh((r*a) @ Uh + x); a' = z*a + (1-z)*h
        {
            float b0 = 0.f, b1 = 0.f;
            const _Float16* rbase = raH + (kh << 7);
            #define S2(j, WJ) { \
                half8_t rv = *(const half8_t*)(rbase + (j)*8); \
                b0 = fdot2f(H2(rv,0), H2(WJ,0), b0); \
                b1 = fdot2f(H2(rv,1), H2(WJ,1), b1); \
                b0 = fdot2f(H2(rv,2), H2(WJ,2), b0); \
                b1 = fdot2f(H2(rv,3), H2(WJ,3), b1); }
            S2(0,  wb0)  S2(1,  wb1)  S2(2,  wb2)  S2(3,  wb3)
            S2(4,  wb4)  S2(5,  wb5)  S2(6,  wb6)  S2(7,  wb7)
            S2(8,  wb8)  S2(9,  wb9)  S2(10, wb10) S2(11, wb11)
            S2(12, wb12) S2(13, wb13) S2(14, wb14) S2(15, wb15)
            #undef S2
            float hs = b0 + b1;
            hs += __shfl_xor(hs, 1, 64);                       // combine K-halves
            if (kh == 0) {
                float h  = fast_tanh(hs + x2c);
                float z  = zS[hcol];
                float an = z * aF[hcol] + (1.0f - z) * h;
                aF[hcol] = an;
                aH[hcol] = (_Float16)an;
            }
        }
        __syncthreads();
    }

    if (tid < U_SZ) out[(size_t)b * U_SZ + tid] = aF[tid];
}

// ---------------------------------------------------------------------------
extern "C" void kernel_launch(void* const* d_in, const int* in_sizes, int n_in,
                              void* d_out, int out_size, void* d_ws, size_t ws_size,
                              hipStream_t stream)
{
    const float* X    = (const float*)d_in[0];   // (64,2048,256)
    const float* W    = (const float*)d_in[1];   // (256,768)
    const float* RK   = (const float*)d_in[2];   // (256,768)
    const float* bias = (const float*)d_in[3];   // (768,)
    _Float16* proj = (_Float16*)d_ws;            // 131072*768*2 = 201.3 MB

    proj_gemm<<<MT_M * NT_N, 256, 0, stream>>>(X, W, bias, proj);
    gru_scan<<<B_SZ, 512, 0, stream>>>(RK, proj, (float*)d_out);
}